// Round 2
// baseline (2073.735 us; speedup 1.0000x reference)
//
#include <hip/hip_runtime.h>
#include <hip/hip_bf16.h>

#define N_NODES   50000
#define N_EDGES   800000
#define IN_DIM    128
#define EDGE_DIM  32
#define HIDDEN    128
#define NUM_LAYERS 3
#define BN_EPS    1e-5f
#define RES_SCALE 0.1f

// ---------------- copy x -> h (fp32) ----------------
__global__ __launch_bounds__(256) void convert_kernel(const float* __restrict__ x,
                                                      float* __restrict__ h) {
    int idx = blockIdx.x * 256 + threadIdx.x;
    if (idx < N_NODES * HIDDEN) h[idx] = x[idx];
}

// ---------------- zero agg + stats ----------------
__global__ __launch_bounds__(256) void zero_kernel(float* __restrict__ agg,
                                                   float* __restrict__ stats) {
    int idx = blockIdx.x * 256 + threadIdx.x;
    if (idx < N_NODES * HIDDEN) agg[idx] = 0.f;
    if (idx < 2 * HIDDEN) stats[idx] = 0.f;
}

// ---------------- fused edge message + scatter-add ----------------
// msg = relu(h[src] + edge_attr @ We + be);  agg[dst] += msg
__global__ __launch_bounds__(256) void edge_kernel(
    const float* __restrict__ h, const float* __restrict__ edge_attr,
    const int* __restrict__ ei, const float* __restrict__ We,
    const float* __restrict__ be, float* __restrict__ agg) {
    __shared__ float wcol_s[EDGE_DIM][HIDDEN];  // 16 KB
    int t = threadIdx.x;
    int f = t & 127;
    int sub = t >> 7;  // which of the 2 edges this block processes per step

    for (int i = t; i < EDGE_DIM * HIDDEN; i += 256)
        wcol_s[i >> 7][i & 127] = We[i];
    __syncthreads();

    float wcol[EDGE_DIM];
#pragma unroll
    for (int k = 0; k < EDGE_DIM; k++) wcol[k] = wcol_s[k][f];
    float bias = be[f];

    int slot = blockIdx.x * 2 + sub;
    int nslots = gridDim.x * 2;
    for (int e = slot; e < N_EDGES; e += nslots) {
        int src = ei[e];
        int dst = ei[N_EDGES + e];
        const float4* eap = (const float4*)(edge_attr + (size_t)e * EDGE_DIM);
        float acc = bias;
#pragma unroll
        for (int q = 0; q < 8; q++) {
            float4 p = eap[q];
            acc = fmaf(p.x, wcol[q * 4 + 0], acc);
            acc = fmaf(p.y, wcol[q * 4 + 1], acc);
            acc = fmaf(p.z, wcol[q * 4 + 2], acc);
            acc = fmaf(p.w, wcol[q * 4 + 3], acc);
        }
        float msg = acc + h[(size_t)src * HIDDEN + f];
        msg = fmaxf(msg, 0.f);
        unsafeAtomicAdd(&agg[(size_t)dst * HIDDEN + f], msg);
    }
}

// ---------------- 128-wide node GEMM, K-tiled (all fp32) ----------------
// out = act(in (+ in2) @ W + b); optional per-feature sum/sumsq stats
template <int ADD2, int RELU, int STATS>
__global__ __launch_bounds__(256) void gemm128_kernel(
    const float* __restrict__ in, const float* __restrict__ in2,
    const float* __restrict__ W, const float* __restrict__ bias,
    float* __restrict__ out, float* __restrict__ stats) {
    __shared__ float Wt[32][HIDDEN];        // 16 KB: K-panel of W
    __shared__ float zt[32][33];            // 4.3 KB padded: 32 nodes x 32 k
    __shared__ float red[8][32][4][2];      // 8 KB: stats reduction
    int t = threadIdx.x;
    int base = blockIdx.x * 32;
    int ng = t >> 5, fg = t & 31;  // 8 node-groups x 32 feature-groups

    float acc[4][4];
#pragma unroll
    for (int i = 0; i < 4; i++)
#pragma unroll
        for (int j = 0; j < 4; j++) acc[i][j] = 0.f;

    for (int kt = 0; kt < 4; kt++) {
        int k0 = kt * 32;
        for (int i = t; i < 32 * HIDDEN; i += 256) {
            int kk = i >> 7, ff = i & 127;
            Wt[kk][ff] = W[(size_t)(k0 + kk) * HIDDEN + ff];
        }
        for (int i = t; i < 32 * 32; i += 256) {
            int n = i >> 5, kk = i & 31;
            int gn = base + n;
            float v = 0.f;
            if (gn < N_NODES) {
                size_t off = (size_t)gn * HIDDEN + k0 + kk;
                v = in[off];
                if (ADD2) v += in2[off];
            }
            zt[n][kk] = v;
        }
        __syncthreads();
#pragma unroll 4
        for (int kk = 0; kk < 32; kk++) {
            float zv[4];
#pragma unroll
            for (int i = 0; i < 4; i++) zv[i] = zt[ng * 4 + i][kk];
            float4 wv = *(const float4*)&Wt[kk][fg * 4];
            float wf[4] = {wv.x, wv.y, wv.z, wv.w};
#pragma unroll
            for (int i = 0; i < 4; i++)
#pragma unroll
                for (int j = 0; j < 4; j++)
                    acc[i][j] = fmaf(zv[i], wf[j], acc[i][j]);
        }
        __syncthreads();
    }

    float bv[4];
#pragma unroll
    for (int j = 0; j < 4; j++) bv[j] = bias[fg * 4 + j];
#pragma unroll
    for (int i = 0; i < 4; i++) {
        int gn = base + ng * 4 + i;
#pragma unroll
        for (int j = 0; j < 4; j++) {
            float v = acc[i][j] + bv[j];
            if (RELU) v = fmaxf(v, 0.f);
            acc[i][j] = v;
        }
        if (gn < N_NODES) {
            float4 st = make_float4(acc[i][0], acc[i][1], acc[i][2], acc[i][3]);
            *(float4*)&out[(size_t)gn * HIDDEN + fg * 4] = st;
        }
    }

    if (STATS) {
        float s[4] = {0.f, 0.f, 0.f, 0.f}, sq[4] = {0.f, 0.f, 0.f, 0.f};
#pragma unroll
        for (int i = 0; i < 4; i++) {
            int gn = base + ng * 4 + i;
            if (gn < N_NODES) {
#pragma unroll
                for (int j = 0; j < 4; j++) {
                    s[j] += acc[i][j];
                    sq[j] = fmaf(acc[i][j], acc[i][j], sq[j]);
                }
            }
        }
#pragma unroll
        for (int j = 0; j < 4; j++) {
            red[ng][fg][j][0] = s[j];
            red[ng][fg][j][1] = sq[j];
        }
        __syncthreads();
        if (t < HIDDEN) {
            int ffg = t >> 2, jj = t & 3;
            float ts = 0.f, tq = 0.f;
            for (int g = 0; g < 8; g++) {
                ts += red[g][ffg][jj][0];
                tq += red[g][ffg][jj][1];
            }
            unsafeAtomicAdd(&stats[t], ts);
            unsafeAtomicAdd(&stats[HIDDEN + t], tq);
        }
    }
}

// ---------------- batchnorm + relu + residual ----------------
__global__ __launch_bounds__(256) void bn_kernel(
    const float* __restrict__ z2, const float* __restrict__ stats,
    const float* __restrict__ gamma, const float* __restrict__ beta,
    float* __restrict__ h, float* __restrict__ out, int write_out) {
    int idx = blockIdx.x * 256 + threadIdx.x;
    if (idx >= N_NODES * HIDDEN) return;
    int f = idx & 127;
    const float inv_n = 1.0f / (float)N_NODES;
    float mu = stats[f] * inv_n;
    float var = stats[HIDDEN + f] * inv_n - mu * mu;
    float inv = rsqrtf(var + BN_EPS);
    float g = gamma[f], bt = beta[f];
    float z = (z2[idx] - mu) * inv * g + bt;
    z = fmaxf(z, 0.f);
    float hn = fmaf(RES_SCALE, h[idx], z);
    h[idx] = hn;
    if (write_out) out[idx] = hn;
}

extern "C" void kernel_launch(void* const* d_in, const int* in_sizes, int n_in,
                              void* d_out, int out_size, void* d_ws, size_t ws_size,
                              hipStream_t stream) {
    const float* x     = (const float*)d_in[0];
    const int*   ei    = (const int*)d_in[1];
    const float* ea    = (const float*)d_in[2];
    const float* We    = (const float*)d_in[3];
    const float* be    = (const float*)d_in[4];
    const float* W1    = (const float*)d_in[5];
    const float* b1    = (const float*)d_in[6];
    const float* W2    = (const float*)d_in[7];
    const float* b2    = (const float*)d_in[8];
    const float* gamma = (const float*)d_in[9];
    const float* beta  = (const float*)d_in[10];
    float* out = (float*)d_out;

    float* ws = (float*)d_ws;
    const size_t NH = (size_t)N_NODES * HIDDEN;
    float* h     = ws;
    float* agg   = h + NH;    // reused as z2 output of gemm2
    float* t1    = agg + NH;
    float* stats = t1 + NH;   // 256 floats

    const int nh_blocks = (N_NODES * HIDDEN + 255) / 256;  // 25000

    convert_kernel<<<nh_blocks, 256, 0, stream>>>(x, h);
    for (int l = 0; l < NUM_LAYERS; l++) {
        zero_kernel<<<nh_blocks, 256, 0, stream>>>(agg, stats);
        edge_kernel<<<2048, 256, 0, stream>>>(
            h, ea, ei, We + (size_t)l * EDGE_DIM * HIDDEN, be + (size_t)l * HIDDEN, agg);
        gemm128_kernel<1, 1, 0><<<(N_NODES + 31) / 32, 256, 0, stream>>>(
            h, agg, W1 + (size_t)l * HIDDEN * HIDDEN, b1 + (size_t)l * HIDDEN, t1, nullptr);
        gemm128_kernel<0, 0, 1><<<(N_NODES + 31) / 32, 256, 0, stream>>>(
            t1, nullptr, W2 + (size_t)l * HIDDEN * HIDDEN, b2 + (size_t)l * HIDDEN, agg, stats);
        bn_kernel<<<nh_blocks, 256, 0, stream>>>(
            agg, stats, gamma + (size_t)l * HIDDEN, beta + (size_t)l * HIDDEN,
            h, out, (l == NUM_LAYERS - 1) ? 1 : 0);
    }
}